// Round 1
// baseline (1824.106 us; speedup 1.0000x reference)
//
#include <hip/hip_runtime.h>

typedef __bf16 bf16x8 __attribute__((ext_vector_type(8)));
typedef float f32x4 __attribute__((ext_vector_type(4)));

#define LDSPAD 72   // 64 + 8 bf16 pad: 144B row stride -> 2 lanes/bank on ds_read_b128 (free)

// ---------------- DFT basis build: BT[n][j], n<2050: k=n>>1, cos/sin(2*pi*k*(544+j)/2048) ----------------
__global__ __launch_bounds__(256) void build_bdft(__bf16* __restrict__ BT)
{
    int id = blockIdx.x * 256 + threadIdx.x;
    if (id >= 2176 * 960) return;
    int n = id / 960;
    int j = id - n * 960;
    float v = 0.f;
    if (n < 2050) {
        int k = n >> 1;
        int p = (k * (544 + j)) & 2047;                // exact integer phase reduction
        float ang = (float)p * 0.0030679615757712823f; // 2*pi/2048
        v = (n & 1) ? sinf(ang) : cosf(ang);           // sign of sin irrelevant (squared)
    }
    BT[id] = (__bf16)v;
}

// ---------------- windowed frames: A[frame][j] = xp[t*240+544+j] * hann960[j], bf16 ----------------
__global__ __launch_bounds__(256) void build_frames(const float* __restrict__ x, __bf16* __restrict__ A)
{
    int id = blockIdx.x * 256 + threadIdx.x;           // one thread per 2 cols
    if (id >= 16128 * 480) return;
    int frame = id / 480;
    int jp = (id - frame * 480) * 2;
    float v[2] = {0.f, 0.f};
    if (frame < 16016) {
        int b = frame / 1001;
        int t = frame - b * 1001;
        const float* xb = x + (size_t)b * 240000;
        #pragma unroll
        for (int e = 0; e < 2; ++e) {
            int j = jp + e;
            int s = t * 240 + j - 480;                 // xp index minus pad
            if (s < 0) s = -s;                         // left reflect
            else if (s >= 240000) s = 479998 - s;      // right reflect (2L-2-s)
            float win = 0.5f - 0.5f * cosf((float)j * 0.006544984694978735f); // 2*pi/960
            v[e] = xb[s] * win;
        }
    }
    union { unsigned int u; __bf16 h[2]; } pk;
    pk.h[0] = (__bf16)v[0]; pk.h[1] = (__bf16)v[1];
    *reinterpret_cast<unsigned int*>(&A[(size_t)frame * 960 + jp]) = pk.u;
}

// ---------------- bf16 MFMA GEMM, C = A(M x Ka) * BT(N x Ka)^T.  mode 0: DFT (store bf16 C)
// mode 1: input projection (scatter fp32 into LSTM-layout `pre` with bias) ----------------
__global__ __launch_bounds__(256) void gemm_kernel(
    const __bf16* __restrict__ A, const __bf16* __restrict__ BT,
    int Ka, int kIters, int mode,
    __bf16* __restrict__ Cdft, float* __restrict__ pre,
    const float* __restrict__ b_f, const float* __restrict__ b_b)
{
    __shared__ __bf16 As[128 * LDSPAD];
    __shared__ __bf16 Bs[128 * LDSPAD];
    const int tid = threadIdx.x;
    const int wave = tid >> 6, lane = tid & 63, l15 = lane & 15, quad = lane >> 4;
    const int bn = blockIdx.x, bm = blockIdx.y;
    const int qm = wave >> 1, qn = wave & 1;
    f32x4 acc[4][4] = {};
    const int rowS = tid >> 3;          // 0..31
    const int colS = (tid & 7) * 8;     // 0..56
    const __bf16* Ag = A + (size_t)(bm * 128) * Ka;
    const __bf16* Bg = BT + (size_t)(bn * 128) * Ka;

    for (int kb = 0; kb < kIters; ++kb) {
        int k0 = kb * 64;
        #pragma unroll
        for (int p = 0; p < 4; ++p) {
            int row = p * 32 + rowS;
            *reinterpret_cast<uint4*>(&As[row * LDSPAD + colS]) =
                *reinterpret_cast<const uint4*>(&Ag[(size_t)row * Ka + k0 + colS]);
            *reinterpret_cast<uint4*>(&Bs[row * LDSPAD + colS]) =
                *reinterpret_cast<const uint4*>(&Bg[(size_t)row * Ka + k0 + colS]);
        }
        __syncthreads();
        #pragma unroll
        for (int ks = 0; ks < 2; ++ks) {
            bf16x8 af[4], bfr[4];
            #pragma unroll
            for (int i = 0; i < 4; ++i)
                af[i] = *reinterpret_cast<const bf16x8*>(&As[(qm * 64 + i * 16 + l15) * LDSPAD + ks * 32 + quad * 8]);
            #pragma unroll
            for (int j = 0; j < 4; ++j)
                bfr[j] = *reinterpret_cast<const bf16x8*>(&Bs[(qn * 64 + j * 16 + l15) * LDSPAD + ks * 32 + quad * 8]);
            #pragma unroll
            for (int i = 0; i < 4; ++i)
                #pragma unroll
                for (int j = 0; j < 4; ++j)
                    acc[i][j] = __builtin_amdgcn_mfma_f32_16x16x32_bf16(af[i], bfr[j], acc[i][j], 0, 0, 0);
        }
        __syncthreads();
    }

    if (mode == 0) {
        #pragma unroll
        for (int i = 0; i < 4; ++i)
            #pragma unroll
            for (int j = 0; j < 4; ++j) {
                int n = bn * 128 + qn * 64 + j * 16 + l15;
                #pragma unroll
                for (int r = 0; r < 4; ++r) {
                    int m = bm * 128 + qm * 64 + i * 16 + quad * 4 + r;
                    Cdft[(size_t)m * 2176 + n] = (__bf16)acc[i][j][r];
                }
            }
    } else {
        for (int i = 0; i < 4; ++i)
            for (int j = 0; j < 4; ++j) {
                int n = bn * 128 + qn * 64 + j * 16 + l15;   // n < 1024
                float bias = (n < 512) ? b_f[n] : b_b[n - 512];
                int dirg = n >> 9;
                int g = (n >> 7) & 3;
                int jj = n & 127;
                int w8 = jj >> 4, jl = jj & 15;
                for (int r = 0; r < 4; ++r) {
                    int m = bm * 128 + qm * 64 + i * 16 + quad * 4 + r;
                    if (m < 16016) {
                        int b = m / 1001;
                        int t = m - b * 1001;
                        int lane2 = (b >> 2) * 16 + jl;
                        int r2 = b & 3;
                        size_t off = (((size_t)(t * 2 + dirg) * 8 + w8) * 64 + lane2) * 16 + g * 4 + r2;
                        pre[off] = acc[i][j][r] + bias;
                    }
                }
            }
    }
}

// ---------------- feature build: gather harmonic energies from bf16 DFT output ----------------
__global__ __launch_bounds__(320) void build_feat(const float* __restrict__ f0,
    const __bf16* __restrict__ Cdft, __bf16* __restrict__ feat)
{
    int frame = blockIdx.x;
    int d = threadIdx.x;   // 0..319
    float val = 0.f;
    if (frame < 16016) {
        int b = frame / 1001;
        int t = frame - b * 1001;
        float f0v = f0[b * 1001 + t];
        float f0nz = (f0v > 0.f) ? f0v : 80.f;   // SR/NUM_BANDS*0.5
        if (d < 300) {
            float mult = (d == 0) ? 0.5f : (float)(d + 1) * 0.5f;
            float harm = f0nz * mult;
            int kidx = (int)rintf(harm * (1.0f / 11.71875f));  // FREQ_INTERVAL = 24000/2048
            kidx = min(max(kidx, 0), 1024);
            float e = 0.f;
            if (kidx < 1024) {   // bin 1024 forced to zero by reference
                unsigned int pk = *reinterpret_cast<const unsigned int*>(&Cdft[(size_t)frame * 2176 + 2 * kidx]);
                union { unsigned int u; __bf16 h[2]; } c; c.u = pk;
                float c0 = (float)c.h[0], c1 = (float)c.h[1];
                e = c0 * c0 + c1 * c1;
            }
            val = (logf(e + 1e-8f) + 18.f) * (1.f / 23.f);
        } else if (d == 300) {
            val = logf(f0nz);
        }
    }
    feat[(size_t)frame * 320 + d] = (__bf16)val;
}

// ---------------- stacked input-projection weights, transposed + K-padded, bf16 ----------------
__global__ __launch_bounds__(256) void build_wt(const float* __restrict__ w_ih_f,
    const float* __restrict__ w_ih_b, __bf16* __restrict__ WT)
{
    int id = blockIdx.x * 256 + threadIdx.x;
    if (id >= 1024 * 320) return;
    int n = id / 320;
    int k = id - n * 320;
    float v = 0.f;
    if (k < 301) v = (n < 512) ? w_ih_f[n * 301 + k] : w_ih_b[(n - 512) * 301 + k];
    WT[id] = (__bf16)v;
}

// ---------------- persistent BiLSTM: 1 block per direction, 8 waves, w_hh in register fragments ----------------
__global__ __launch_bounds__(512) void lstm_kernel(
    const float* __restrict__ w_hh_f, const float* __restrict__ w_hh_b,
    const float* __restrict__ pre, float* __restrict__ h_out)
{
    const int dir = blockIdx.x;
    const float* w_hh = dir ? w_hh_b : w_hh_f;
    const int tid = threadIdx.x;
    const int wave = tid >> 6, lane = tid & 63, l15 = lane & 15, quad = lane >> 4;
    __shared__ __bf16 h_lds[16 * 128];
    for (int i = tid; i < 2048; i += 512) h_lds[i] = (__bf16)0.0f;

    // B-fragments: bw[g][kt] holds w_hh[n = g*128 + wave*16 + l15][kt*32 + quad*8 + e]
    bf16x8 bw[4][4];
    #pragma unroll
    for (int g = 0; g < 4; ++g)
        #pragma unroll
        for (int kt = 0; kt < 4; ++kt) {
            const float* wp = w_hh + (size_t)(g * 128 + wave * 16 + l15) * 128 + kt * 32 + quad * 8;
            bf16x8 v;
            #pragma unroll
            for (int e = 0; e < 8; ++e) v[e] = (__bf16)wp[e];
            bw[g][kt] = v;
        }

    float c[4] = {0.f, 0.f, 0.f, 0.f};
    const float L2E = 1.4426950408889634f;

    int tt0 = dir ? 1000 : 0;
    f32x4 pc[4];
    {
        const f32x4* pp = reinterpret_cast<const f32x4*>(pre + (((size_t)(tt0 * 2 + dir) * 8 + wave) * 64 + lane) * 16);
        #pragma unroll
        for (int g = 0; g < 4; ++g) pc[g] = pp[g];
    }
    __syncthreads();

    for (int step = 0; step <= 1000; ++step) {
        int tt = dir ? (1000 - step) : step;
        int stepn = (step < 1000) ? step + 1 : step;
        int ttn = dir ? (1000 - stepn) : stepn;
        // prefetch next step's pre (hides HBM latency behind this step's compute)
        f32x4 pn[4];
        {
            const f32x4* pp = reinterpret_cast<const f32x4*>(pre + (((size_t)(ttn * 2 + dir) * 8 + wave) * 64 + lane) * 16);
            #pragma unroll
            for (int g = 0; g < 4; ++g) pn[g] = pp[g];
        }
        // A fragments of h(t-1) from LDS
        bf16x8 a[4];
        #pragma unroll
        for (int kt = 0; kt < 4; ++kt)
            a[kt] = *reinterpret_cast<const bf16x8*>(&h_lds[l15 * 128 + kt * 32 + quad * 8]);
        __syncthreads();   // all waves done reading h(t-1) before anyone overwrites

        f32x4 z[4];
        #pragma unroll
        for (int g = 0; g < 4; ++g) {
            f32x4 accg = pc[g];   // acc init = pre (saves the adds)
            #pragma unroll
            for (int kt = 0; kt < 4; ++kt)
                accg = __builtin_amdgcn_mfma_f32_16x16x32_bf16(a[kt], bw[g][kt], accg, 0, 0, 0);
            z[g] = accg;
        }
        #pragma unroll
        for (int r = 0; r < 4; ++r) {
            float zi = z[0][r], zf = z[1][r], zg = z[2][r], zo = z[3][r];
            float si = __builtin_amdgcn_rcpf(1.f + exp2f(-L2E * zi));
            float sf = __builtin_amdgcn_rcpf(1.f + exp2f(-L2E * zf));
            float tg = 2.f * __builtin_amdgcn_rcpf(1.f + exp2f(-2.f * L2E * zg)) - 1.f;
            float so = __builtin_amdgcn_rcpf(1.f + exp2f(-L2E * zo));
            float cn = sf * c[r] + si * tg;
            c[r] = cn;
            float th = 2.f * __builtin_amdgcn_rcpf(1.f + exp2f(-2.f * L2E * cn)) - 1.f;
            float h = so * th;
            int b = quad * 4 + r;
            int j = wave * 16 + l15;
            h_lds[b * 128 + j] = (__bf16)h;
            h_out[(((size_t)dir * 1001 + tt) * 16 + b) * 128 + j] = h;
        }
        #pragma unroll
        for (int g = 0; g < 4; ++g) pc[g] = pn[g];
        __syncthreads();   // h(t) visible to all waves
    }
}

// ---------------- LayerNorm(concat(hf,hb)) + out projection; one wave per (b,t) row ----------------
__global__ __launch_bounds__(256) void out_kernel(
    const float* __restrict__ h_out, const float* __restrict__ ln_g, const float* __restrict__ ln_b,
    const float* __restrict__ out_w, const float* __restrict__ out_b, float* __restrict__ out)
{
    __shared__ __bf16 w_lds[256 * 66];   // [k][o], padded: conflict-free both directions
    __shared__ float hn_lds[4 * 256];
    const int tid = threadIdx.x;
    const int wave = tid >> 6, lane = tid & 63;
    for (int idx = tid; idx < 16384; idx += 256) {
        int o = idx >> 8, k = idx & 255;
        w_lds[k * 66 + o] = (__bf16)out_w[o * 256 + k];
    }
    int r = blockIdx.x * 4 + wave;       // < 16016
    int b = r / 1001, t = r - b * 1001;
    size_t basef = (((size_t)0 * 1001 + t) * 16 + b) * 128;
    size_t baseb = (((size_t)1 * 1001 + t) * 16 + b) * 128;
    float h0 = h_out[basef + lane];
    float h1 = h_out[basef + 64 + lane];
    float h2 = h_out[baseb + lane];
    float h3 = h_out[baseb + 64 + lane];
    float s1 = h0 + h1 + h2 + h3;
    float s2 = h0 * h0 + h1 * h1 + h2 * h2 + h3 * h3;
    #pragma unroll
    for (int m = 32; m >= 1; m >>= 1) {
        s1 += __shfl_xor(s1, m, 64);
        s2 += __shfl_xor(s2, m, 64);
    }
    float mu = s1 * (1.f / 256.f);
    float var = s2 * (1.f / 256.f) - mu * mu;   // biased var, matches jnp var
    float rstd = rsqrtf(var + 1e-5f);
    int k0 = lane, k1 = 64 + lane, k2 = 128 + lane, k3 = 192 + lane;
    hn_lds[wave * 256 + k0] = (h0 - mu) * rstd * ln_g[k0] + ln_b[k0];
    hn_lds[wave * 256 + k1] = (h1 - mu) * rstd * ln_g[k1] + ln_b[k1];
    hn_lds[wave * 256 + k2] = (h2 - mu) * rstd * ln_g[k2] + ln_b[k2];
    hn_lds[wave * 256 + k3] = (h3 - mu) * rstd * ln_g[k3] + ln_b[k3];
    __syncthreads();
    const float* hn = &hn_lds[wave * 256];
    float acc = 0.f;
    #pragma unroll 4
    for (int k = 0; k < 256; ++k)
        acc += hn[k] * (float)w_lds[k * 66 + lane];   // hn[k]: LDS broadcast
    out[(size_t)r * 64 + lane] = acc + out_b[lane];
}

extern "C" void kernel_launch(void* const* d_in, const int* in_sizes, int n_in,
                              void* d_out, int out_size, void* d_ws, size_t ws_size,
                              hipStream_t stream) {
    const float* x      = (const float*)d_in[0];
    const float* f0     = (const float*)d_in[1];
    const float* w_ih_f = (const float*)d_in[2];
    const float* w_hh_f = (const float*)d_in[3];
    const float* b_f    = (const float*)d_in[4];
    const float* w_ih_b = (const float*)d_in[5];
    const float* w_hh_b = (const float*)d_in[6];
    const float* b_b    = (const float*)d_in[7];
    const float* ln_g   = (const float*)d_in[8];
    const float* ln_b   = (const float*)d_in[9];
    const float* out_w  = (const float*)d_in[10];
    const float* out_b  = (const float*)d_in[11];
    float* out = (float*)d_out;

    char* ws = (char*)d_ws;
    size_t off = 0;
    auto alloc = [&](size_t bytes) { size_t o = off; off = (off + bytes + 255) & ~(size_t)255; return o; };
    __bf16* A     = (__bf16*)(ws + alloc((size_t)16128 * 960 * 2));
    __bf16* BT    = (__bf16*)(ws + alloc((size_t)2176 * 960 * 2));
    __bf16* Cdft  = (__bf16*)(ws + alloc((size_t)16128 * 2176 * 2));
    __bf16* feat  = (__bf16*)(ws + alloc((size_t)16128 * 320 * 2));
    __bf16* WT    = (__bf16*)(ws + alloc((size_t)1024 * 320 * 2));
    float*  pre   = (float*)(ws + alloc((size_t)1001 * 16384 * 4));
    float*  h_out = (float*)(ws + alloc((size_t)2 * 1001 * 16 * 128 * 4));
    (void)ws_size; (void)in_sizes; (void)n_in; (void)out_size;

    build_bdft  <<<(2176 * 960 + 255) / 256, 256, 0, stream>>>(BT);
    build_frames<<<(16128 * 480 + 255) / 256, 256, 0, stream>>>(x, A);
    gemm_kernel <<<dim3(17, 126), 256, 0, stream>>>(A, BT, 960, 15, 0, Cdft, nullptr, nullptr, nullptr);
    build_feat  <<<16128, 320, 0, stream>>>(f0, Cdft, feat);
    build_wt    <<<(1024 * 320 + 255) / 256, 256, 0, stream>>>(w_ih_f, w_ih_b, WT);
    gemm_kernel <<<dim3(8, 126), 256, 0, stream>>>(feat, WT, 320, 5, 1, nullptr, pre, b_f, b_b);
    lstm_kernel <<<2, 512, 0, stream>>>(w_hh_f, w_hh_b, pre, h_out);
    out_kernel  <<<4004, 256, 0, stream>>>(h_out, ln_g, ln_b, out_w, out_b, out);
}

// Round 2
// 1457.156 us; speedup vs baseline: 1.2518x; 1.2518x over previous
//
#include <hip/hip_runtime.h>

typedef __bf16 bf16x8 __attribute__((ext_vector_type(8)));
typedef float f32x4 __attribute__((ext_vector_type(4)));

#define LDSPAD 72   // 64 + 8 bf16 pad: 144B row stride -> 2 lanes/bank on ds_read_b128 (free)

// LDS-only barrier: does NOT drain vmcnt, so global prefetch loads / fire-and-forget
// stores stay in flight across the barrier (CK block_sync_lds pattern).
__device__ __forceinline__ void sync_lds() {
    asm volatile("s_waitcnt lgkmcnt(0)" ::: "memory");
    __builtin_amdgcn_s_barrier();
}

// ---------------- DFT basis build: BT[n][j], n<2050: k=n>>1, cos/sin(2*pi*k*(544+j)/2048) ----------------
__global__ __launch_bounds__(256) void build_bdft(__bf16* __restrict__ BT)
{
    int id = blockIdx.x * 256 + threadIdx.x;
    if (id >= 2176 * 960) return;
    int n = id / 960;
    int j = id - n * 960;
    float v = 0.f;
    if (n < 2050) {
        int k = n >> 1;
        int p = (k * (544 + j)) & 2047;                // exact integer phase reduction
        float ang = (float)p * 0.0030679615757712823f; // 2*pi/2048
        v = (n & 1) ? sinf(ang) : cosf(ang);           // sign of sin irrelevant (squared)
    }
    BT[id] = (__bf16)v;
}

// ---------------- windowed frames: A[frame][j] = xp[t*240+544+j] * hann960[j], bf16 ----------------
__global__ __launch_bounds__(256) void build_frames(const float* __restrict__ x, __bf16* __restrict__ A)
{
    int id = blockIdx.x * 256 + threadIdx.x;           // one thread per 2 cols
    if (id >= 16128 * 480) return;
    int frame = id / 480;
    int jp = (id - frame * 480) * 2;
    float v[2] = {0.f, 0.f};
    if (frame < 16016) {
        int b = frame / 1001;
        int t = frame - b * 1001;
        const float* xb = x + (size_t)b * 240000;
        #pragma unroll
        for (int e = 0; e < 2; ++e) {
            int j = jp + e;
            int s = t * 240 + j - 480;                 // xp index minus pad
            if (s < 0) s = -s;                         // left reflect
            else if (s >= 240000) s = 479998 - s;      // right reflect (2L-2-s)
            float win = 0.5f - 0.5f * cosf((float)j * 0.006544984694978735f); // 2*pi/960
            v[e] = xb[s] * win;
        }
    }
    union { unsigned int u; __bf16 h[2]; } pk;
    pk.h[0] = (__bf16)v[0]; pk.h[1] = (__bf16)v[1];
    *reinterpret_cast<unsigned int*>(&A[(size_t)frame * 960 + jp]) = pk.u;
}

// ---------------- bf16 MFMA GEMM, C = A(M x Ka) * BT(N x Ka)^T.  mode 0: DFT (store bf16 C)
// mode 1: input projection (scatter fp32 into LSTM-layout `pre` with bias) ----------------
__global__ __launch_bounds__(256) void gemm_kernel(
    const __bf16* __restrict__ A, const __bf16* __restrict__ BT,
    int Ka, int kIters, int mode,
    __bf16* __restrict__ Cdft, float* __restrict__ pre,
    const float* __restrict__ b_f, const float* __restrict__ b_b)
{
    __shared__ __bf16 As[128 * LDSPAD];
    __shared__ __bf16 Bs[128 * LDSPAD];
    const int tid = threadIdx.x;
    const int wave = tid >> 6, lane = tid & 63, l15 = lane & 15, quad = lane >> 4;
    const int bn = blockIdx.x, bm = blockIdx.y;
    const int qm = wave >> 1, qn = wave & 1;
    f32x4 acc[4][4] = {};
    const int rowS = tid >> 3;          // 0..31
    const int colS = (tid & 7) * 8;     // 0..56
    const __bf16* Ag = A + (size_t)(bm * 128) * Ka;
    const __bf16* Bg = BT + (size_t)(bn * 128) * Ka;

    for (int kb = 0; kb < kIters; ++kb) {
        int k0 = kb * 64;
        #pragma unroll
        for (int p = 0; p < 4; ++p) {
            int row = p * 32 + rowS;
            *reinterpret_cast<uint4*>(&As[row * LDSPAD + colS]) =
                *reinterpret_cast<const uint4*>(&Ag[(size_t)row * Ka + k0 + colS]);
            *reinterpret_cast<uint4*>(&Bs[row * LDSPAD + colS]) =
                *reinterpret_cast<const uint4*>(&Bg[(size_t)row * Ka + k0 + colS]);
        }
        __syncthreads();
        #pragma unroll
        for (int ks = 0; ks < 2; ++ks) {
            bf16x8 af[4], bfr[4];
            #pragma unroll
            for (int i = 0; i < 4; ++i)
                af[i] = *reinterpret_cast<const bf16x8*>(&As[(qm * 64 + i * 16 + l15) * LDSPAD + ks * 32 + quad * 8]);
            #pragma unroll
            for (int j = 0; j < 4; ++j)
                bfr[j] = *reinterpret_cast<const bf16x8*>(&Bs[(qn * 64 + j * 16 + l15) * LDSPAD + ks * 32 + quad * 8]);
            #pragma unroll
            for (int i = 0; i < 4; ++i)
                #pragma unroll
                for (int j = 0; j < 4; ++j)
                    acc[i][j] = __builtin_amdgcn_mfma_f32_16x16x32_bf16(af[i], bfr[j], acc[i][j], 0, 0, 0);
        }
        __syncthreads();
    }

    if (mode == 0) {
        #pragma unroll
        for (int i = 0; i < 4; ++i)
            #pragma unroll
            for (int j = 0; j < 4; ++j) {
                int n = bn * 128 + qn * 64 + j * 16 + l15;
                #pragma unroll
                for (int r = 0; r < 4; ++r) {
                    int m = bm * 128 + qm * 64 + i * 16 + quad * 4 + r;
                    Cdft[(size_t)m * 2176 + n] = (__bf16)acc[i][j][r];
                }
            }
    } else {
        for (int i = 0; i < 4; ++i)
            for (int j = 0; j < 4; ++j) {
                int n = bn * 128 + qn * 64 + j * 16 + l15;   // n < 1024
                float bias = (n < 512) ? b_f[n] : b_b[n - 512];
                int dirg = n >> 9;
                int g = (n >> 7) & 3;
                int jj = n & 127;
                int w8 = jj >> 4, jl = jj & 15;
                for (int r = 0; r < 4; ++r) {
                    int m = bm * 128 + qm * 64 + i * 16 + quad * 4 + r;
                    if (m < 16016) {
                        int b = m / 1001;
                        int t = m - b * 1001;
                        int lane2 = (b >> 2) * 16 + jl;
                        int r2 = b & 3;
                        size_t off = (((size_t)(t * 2 + dirg) * 8 + w8) * 64 + lane2) * 16 + g * 4 + r2;
                        pre[off] = acc[i][j][r] + bias;
                    }
                }
            }
    }
}

// ---------------- feature build: gather harmonic energies from bf16 DFT output ----------------
__global__ __launch_bounds__(320) void build_feat(const float* __restrict__ f0,
    const __bf16* __restrict__ Cdft, __bf16* __restrict__ feat)
{
    int frame = blockIdx.x;
    int d = threadIdx.x;   // 0..319
    float val = 0.f;
    if (frame < 16016) {
        int b = frame / 1001;
        int t = frame - b * 1001;
        float f0v = f0[b * 1001 + t];
        float f0nz = (f0v > 0.f) ? f0v : 80.f;   // SR/NUM_BANDS*0.5
        if (d < 300) {
            float mult = (d == 0) ? 0.5f : (float)(d + 1) * 0.5f;
            float harm = f0nz * mult;
            int kidx = (int)rintf(harm * (1.0f / 11.71875f));  // FREQ_INTERVAL = 24000/2048
            kidx = min(max(kidx, 0), 1024);
            float e = 0.f;
            if (kidx < 1024) {   // bin 1024 forced to zero by reference
                unsigned int pk = *reinterpret_cast<const unsigned int*>(&Cdft[(size_t)frame * 2176 + 2 * kidx]);
                union { unsigned int u; __bf16 h[2]; } c; c.u = pk;
                float c0 = (float)c.h[0], c1 = (float)c.h[1];
                e = c0 * c0 + c1 * c1;
            }
            val = (logf(e + 1e-8f) + 18.f) * (1.f / 23.f);
        } else if (d == 300) {
            val = logf(f0nz);
        }
    }
    feat[(size_t)frame * 320 + d] = (__bf16)val;
}

// ---------------- stacked input-projection weights, transposed + K-padded, bf16 ----------------
__global__ __launch_bounds__(256) void build_wt(const float* __restrict__ w_ih_f,
    const float* __restrict__ w_ih_b, __bf16* __restrict__ WT)
{
    int id = blockIdx.x * 256 + threadIdx.x;
    if (id >= 1024 * 320) return;
    int n = id / 320;
    int k = id - n * 320;
    float v = 0.f;
    if (k < 301) v = (n < 512) ? w_ih_f[n * 301 + k] : w_ih_b[(n - 512) * 301 + k];
    WT[id] = (__bf16)v;
}

// ---------------- persistent BiLSTM: 1 block per direction, 8 waves, w_hh in register fragments.
// Double-buffered h in LDS -> ONE LDS-only barrier per step; pre prefetched one step ahead
// (stays in flight across the raw barrier); h_out stores fire-and-forget. ----------------
__global__ __launch_bounds__(512) void lstm_kernel(
    const float* __restrict__ w_hh_f, const float* __restrict__ w_hh_b,
    const float* __restrict__ pre, float* __restrict__ h_out)
{
    const int dir = blockIdx.x;
    const float* w_hh = dir ? w_hh_b : w_hh_f;
    const int tid = threadIdx.x;
    const int wave = tid >> 6, lane = tid & 63, l15 = lane & 15, quad = lane >> 4;
    __shared__ __bf16 h_lds[2][16 * 128];
    for (int i = tid; i < 2048; i += 512) h_lds[0][i] = (__bf16)0.0f;

    // B-fragments: bw[g][kt] holds w_hh[n = g*128 + wave*16 + l15][kt*32 + quad*8 + e]
    bf16x8 bw[4][4];
    #pragma unroll
    for (int g = 0; g < 4; ++g)
        #pragma unroll
        for (int kt = 0; kt < 4; ++kt) {
            const float* wp = w_hh + (size_t)(g * 128 + wave * 16 + l15) * 128 + kt * 32 + quad * 8;
            bf16x8 v;
            #pragma unroll
            for (int e = 0; e < 8; ++e) v[e] = (__bf16)wp[e];
            bw[g][kt] = v;
        }

    float c[4] = {0.f, 0.f, 0.f, 0.f};
    const float L2E = 1.4426950408889634f;

    int tt0 = dir ? 1000 : 0;
    f32x4 pc[4];
    {
        const f32x4* pp = reinterpret_cast<const f32x4*>(pre + (((size_t)(tt0 * 2 + dir) * 8 + wave) * 64 + lane) * 16);
        #pragma unroll
        for (int g = 0; g < 4; ++g) pc[g] = pp[g];
    }
    __syncthreads();   // h_lds[0] init visible

    for (int step = 0; step <= 1000; ++step) {
        int tt = dir ? (1000 - step) : step;
        int stepn = (step < 1000) ? step + 1 : step;
        int ttn = dir ? (1000 - stepn) : stepn;
        // prefetch next step's pre — raw barrier below won't drain these
        f32x4 pn[4];
        {
            const f32x4* pp = reinterpret_cast<const f32x4*>(pre + (((size_t)(ttn * 2 + dir) * 8 + wave) * 64 + lane) * 16);
            #pragma unroll
            for (int g = 0; g < 4; ++g) pn[g] = pp[g];
        }
        // A fragments of h(t-1) from read buffer
        const __bf16* hb = h_lds[step & 1];
        bf16x8 a[4];
        #pragma unroll
        for (int kt = 0; kt < 4; ++kt)
            a[kt] = *reinterpret_cast<const bf16x8*>(&hb[l15 * 128 + kt * 32 + quad * 8]);

        f32x4 z[4];
        #pragma unroll
        for (int g = 0; g < 4; ++g) {
            f32x4 accg = pc[g];   // acc init = pre (saves the adds)
            #pragma unroll
            for (int kt = 0; kt < 4; ++kt)
                accg = __builtin_amdgcn_mfma_f32_16x16x32_bf16(a[kt], bw[g][kt], accg, 0, 0, 0);
            z[g] = accg;
        }
        __bf16* hw = h_lds[(step + 1) & 1];
        #pragma unroll
        for (int r = 0; r < 4; ++r) {
            float zi = z[0][r], zf = z[1][r], zg = z[2][r], zo = z[3][r];
            float si = __builtin_amdgcn_rcpf(1.f + __builtin_amdgcn_exp2f(-L2E * zi));
            float sf = __builtin_amdgcn_rcpf(1.f + __builtin_amdgcn_exp2f(-L2E * zf));
            float tg = 2.f * __builtin_amdgcn_rcpf(1.f + __builtin_amdgcn_exp2f(-2.f * L2E * zg)) - 1.f;
            float so = __builtin_amdgcn_rcpf(1.f + __builtin_amdgcn_exp2f(-L2E * zo));
            float cn = sf * c[r] + si * tg;
            c[r] = cn;
            float th = 2.f * __builtin_amdgcn_rcpf(1.f + __builtin_amdgcn_exp2f(-2.f * L2E * cn)) - 1.f;
            float h = so * th;
            int b = quad * 4 + r;
            int j = wave * 16 + l15;
            hw[b * 128 + j] = (__bf16)h;
            h_out[(((size_t)dir * 1001 + tt) * 16 + b) * 128 + j] = h;   // fire-and-forget
        }
        #pragma unroll
        for (int g = 0; g < 4; ++g) pc[g] = pn[g];
        sync_lds();   // LDS-only barrier: h(t) visible, vmem stays in flight
    }
}

// ---------------- LayerNorm(concat(hf,hb)) + out projection; one wave per (b,t) row ----------------
__global__ __launch_bounds__(256) void out_kernel(
    const float* __restrict__ h_out, const float* __restrict__ ln_g, const float* __restrict__ ln_b,
    const float* __restrict__ out_w, const float* __restrict__ out_b, float* __restrict__ out)
{
    __shared__ __bf16 w_lds[256 * 66];   // [k][o], padded: conflict-free both directions
    __shared__ float hn_lds[4 * 256];
    const int tid = threadIdx.x;
    const int wave = tid >> 6, lane = tid & 63;
    for (int idx = tid; idx < 16384; idx += 256) {
        int o = idx >> 8, k = idx & 255;
        w_lds[k * 66 + o] = (__bf16)out_w[o * 256 + k];
    }
    int r = blockIdx.x * 4 + wave;       // < 16016
    int b = r / 1001, t = r - b * 1001;
    size_t basef = (((size_t)0 * 1001 + t) * 16 + b) * 128;
    size_t baseb = (((size_t)1 * 1001 + t) * 16 + b) * 128;
    float h0 = h_out[basef + lane];
    float h1 = h_out[basef + 64 + lane];
    float h2 = h_out[baseb + lane];
    float h3 = h_out[baseb + 64 + lane];
    float s1 = h0 + h1 + h2 + h3;
    float s2 = h0 * h0 + h1 * h1 + h2 * h2 + h3 * h3;
    #pragma unroll
    for (int m = 32; m >= 1; m >>= 1) {
        s1 += __shfl_xor(s1, m, 64);
        s2 += __shfl_xor(s2, m, 64);
    }
    float mu = s1 * (1.f / 256.f);
    float var = s2 * (1.f / 256.f) - mu * mu;   // biased var, matches jnp var
    float rstd = rsqrtf(var + 1e-5f);
    int k0 = lane, k1 = 64 + lane, k2 = 128 + lane, k3 = 192 + lane;
    hn_lds[wave * 256 + k0] = (h0 - mu) * rstd * ln_g[k0] + ln_b[k0];
    hn_lds[wave * 256 + k1] = (h1 - mu) * rstd * ln_g[k1] + ln_b[k1];
    hn_lds[wave * 256 + k2] = (h2 - mu) * rstd * ln_g[k2] + ln_b[k2];
    hn_lds[wave * 256 + k3] = (h3 - mu) * rstd * ln_g[k3] + ln_b[k3];
    __syncthreads();
    const float* hn = &hn_lds[wave * 256];
    float acc = 0.f;
    #pragma unroll 4
    for (int k = 0; k < 256; ++k)
        acc += hn[k] * (float)w_lds[k * 66 + lane];   // hn[k]: LDS broadcast
    out[(size_t)r * 64 + lane] = acc + out_b[lane];
}

extern "C" void kernel_launch(void* const* d_in, const int* in_sizes, int n_in,
                              void* d_out, int out_size, void* d_ws, size_t ws_size,
                              hipStream_t stream) {
    const float* x      = (const float*)d_in[0];
    const float* f0     = (const float*)d_in[1];
    const float* w_ih_f = (const float*)d_in[2];
    const float* w_hh_f = (const float*)d_in[3];
    const float* b_f    = (const float*)d_in[4];
    const float* w_ih_b = (const float*)d_in[5];
    const float* w_hh_b = (const float*)d_in[6];
    const float* b_b    = (const float*)d_in[7];
    const float* ln_g   = (const float*)d_in[8];
    const float* ln_b   = (const float*)d_in[9];
    const float* out_w  = (const float*)d_in[10];
    const float* out_b  = (const float*)d_in[11];
    float* out = (float*)d_out;

    char* ws = (char*)d_ws;
    size_t off = 0;
    auto alloc = [&](size_t bytes) { size_t o = off; off = (off + bytes + 255) & ~(size_t)255; return o; };
    __bf16* A     = (__bf16*)(ws + alloc((size_t)16128 * 960 * 2));
    __bf16* BT    = (__bf16*)(ws + alloc((size_t)2176 * 960 * 2));
    __bf16* Cdft  = (__bf16*)(ws + alloc((size_t)16128 * 2176 * 2));
    __bf16* feat  = (__bf16*)(ws + alloc((size_t)16128 * 320 * 2));
    __bf16* WT    = (__bf16*)(ws + alloc((size_t)1024 * 320 * 2));
    float*  pre   = (float*)(ws + alloc((size_t)1001 * 16384 * 4));
    float*  h_out = (float*)(ws + alloc((size_t)2 * 1001 * 16 * 128 * 4));
    (void)ws_size; (void)in_sizes; (void)n_in; (void)out_size;

    build_bdft  <<<(2176 * 960 + 255) / 256, 256, 0, stream>>>(BT);
    build_frames<<<(16128 * 480 + 255) / 256, 256, 0, stream>>>(x, A);
    gemm_kernel <<<dim3(17, 126), 256, 0, stream>>>(A, BT, 960, 15, 0, Cdft, nullptr, nullptr, nullptr);
    build_feat  <<<16128, 320, 0, stream>>>(f0, Cdft, feat);
    build_wt    <<<(1024 * 320 + 255) / 256, 256, 0, stream>>>(w_ih_f, w_ih_b, WT);
    gemm_kernel <<<dim3(8, 126), 256, 0, stream>>>(feat, WT, 320, 5, 1, nullptr, pre, b_f, b_b);
    lstm_kernel <<<2, 512, 0, stream>>>(w_hh_f, w_hh_b, pre, h_out);
    out_kernel  <<<4004, 256, 0, stream>>>(h_out, ln_g, ln_b, out_w, out_b, out);
}

// Round 3
// 932.228 us; speedup vs baseline: 1.9567x; 1.5631x over previous
//
#include <hip/hip_runtime.h>

typedef __bf16 bf16x8 __attribute__((ext_vector_type(8)));
typedef float f32x4 __attribute__((ext_vector_type(4)));

#define LDSPAD 72   // 64 + 8 bf16 pad: 144B row stride -> 2 lanes/bank on ds_read_b128 (free)

// LDS-only barrier: does NOT drain vmcnt, so global prefetch loads / fire-and-forget
// stores stay in flight across the barrier (CK block_sync_lds pattern).
__device__ __forceinline__ void sync_lds() {
    asm volatile("s_waitcnt lgkmcnt(0)" ::: "memory");
    __builtin_amdgcn_s_barrier();
}

// ---------------- DFT basis build: BT[n][j], n<2050: k=n>>1, cos/sin(2*pi*k*(544+j)/2048) ----------------
__global__ __launch_bounds__(256) void build_bdft(__bf16* __restrict__ BT)
{
    int id = blockIdx.x * 256 + threadIdx.x;
    if (id >= 2176 * 960) return;
    int n = id / 960;
    int j = id - n * 960;
    float v = 0.f;
    if (n < 2050) {
        int k = n >> 1;
        int p = (k * (544 + j)) & 2047;                // exact integer phase reduction
        float ang = (float)p * 0.0030679615757712823f; // 2*pi/2048
        v = (n & 1) ? sinf(ang) : cosf(ang);           // sign of sin irrelevant (squared)
    }
    BT[id] = (__bf16)v;
}

// ---------------- windowed frames: A[frame][j] = xp[t*240+544+j] * hann960[j], bf16 ----------------
__global__ __launch_bounds__(256) void build_frames(const float* __restrict__ x, __bf16* __restrict__ A)
{
    int id = blockIdx.x * 256 + threadIdx.x;           // one thread per 2 cols
    if (id >= 16128 * 480) return;
    int frame = id / 480;
    int jp = (id - frame * 480) * 2;
    float v[2] = {0.f, 0.f};
    if (frame < 16016) {
        int b = frame / 1001;
        int t = frame - b * 1001;
        const float* xb = x + (size_t)b * 240000;
        #pragma unroll
        for (int e = 0; e < 2; ++e) {
            int j = jp + e;
            int s = t * 240 + j - 480;                 // xp index minus pad
            if (s < 0) s = -s;                         // left reflect
            else if (s >= 240000) s = 479998 - s;      // right reflect (2L-2-s)
            float win = 0.5f - 0.5f * cosf((float)j * 0.006544984694978735f); // 2*pi/960
            v[e] = xb[s] * win;
        }
    }
    union { unsigned int u; __bf16 h[2]; } pk;
    pk.h[0] = (__bf16)v[0]; pk.h[1] = (__bf16)v[1];
    *reinterpret_cast<unsigned int*>(&A[(size_t)frame * 960 + jp]) = pk.u;
}

// ---------------- bf16 MFMA GEMM, C = A(M x Ka) * BT(N x Ka)^T.  mode 0: DFT (store bf16 C)
// mode 1: input projection (scatter fp32 into permuted LSTM-layout `pre` with bias) ----------------
__global__ __launch_bounds__(256) void gemm_kernel(
    const __bf16* __restrict__ A, const __bf16* __restrict__ BT,
    int Ka, int kIters, int mode,
    __bf16* __restrict__ Cdft, float* __restrict__ pre,
    const float* __restrict__ b_f, const float* __restrict__ b_b)
{
    __shared__ __bf16 As[128 * LDSPAD];
    __shared__ __bf16 Bs[128 * LDSPAD];
    const int tid = threadIdx.x;
    const int wave = tid >> 6, lane = tid & 63, l15 = lane & 15, quad = lane >> 4;
    const int bn = blockIdx.x, bm = blockIdx.y;
    const int qm = wave >> 1, qn = wave & 1;
    f32x4 acc[4][4] = {};
    const int rowS = tid >> 3;          // 0..31
    const int colS = (tid & 7) * 8;     // 0..56
    const __bf16* Ag = A + (size_t)(bm * 128) * Ka;
    const __bf16* Bg = BT + (size_t)(bn * 128) * Ka;

    for (int kb = 0; kb < kIters; ++kb) {
        int k0 = kb * 64;
        #pragma unroll
        for (int p = 0; p < 4; ++p) {
            int row = p * 32 + rowS;
            *reinterpret_cast<uint4*>(&As[row * LDSPAD + colS]) =
                *reinterpret_cast<const uint4*>(&Ag[(size_t)row * Ka + k0 + colS]);
            *reinterpret_cast<uint4*>(&Bs[row * LDSPAD + colS]) =
                *reinterpret_cast<const uint4*>(&Bg[(size_t)row * Ka + k0 + colS]);
        }
        __syncthreads();
        #pragma unroll
        for (int ks = 0; ks < 2; ++ks) {
            bf16x8 af[4], bfr[4];
            #pragma unroll
            for (int i = 0; i < 4; ++i)
                af[i] = *reinterpret_cast<const bf16x8*>(&As[(qm * 64 + i * 16 + l15) * LDSPAD + ks * 32 + quad * 8]);
            #pragma unroll
            for (int j = 0; j < 4; ++j)
                bfr[j] = *reinterpret_cast<const bf16x8*>(&Bs[(qn * 64 + j * 16 + l15) * LDSPAD + ks * 32 + quad * 8]);
            #pragma unroll
            for (int i = 0; i < 4; ++i)
                #pragma unroll
                for (int j = 0; j < 4; ++j)
                    acc[i][j] = __builtin_amdgcn_mfma_f32_16x16x32_bf16(af[i], bfr[j], acc[i][j], 0, 0, 0);
        }
        __syncthreads();
    }

    if (mode == 0) {
        #pragma unroll
        for (int i = 0; i < 4; ++i)
            #pragma unroll
            for (int j = 0; j < 4; ++j) {
                int n = bn * 128 + qn * 64 + j * 16 + l15;
                #pragma unroll
                for (int r = 0; r < 4; ++r) {
                    int m = bm * 128 + qm * 64 + i * 16 + quad * 4 + r;
                    Cdft[(size_t)m * 2176 + n] = (__bf16)acc[i][j][r];
                }
            }
    } else {
        for (int i = 0; i < 4; ++i)
            for (int j = 0; j < 4; ++j) {
                int n = bn * 128 + qn * 64 + j * 16 + l15;   // n < 1024
                float bias = (n < 512) ? b_f[n] : b_b[n - 512];
                int dirg = n >> 9;
                int ngate = n & 511;
                int g = ngate >> 7;          // gate index: 0=i 1=f 2=g 3=o
                int jj = ngate & 127;        // hidden unit
                int s = jj * 4 + g;          // permuted slot: one cell's 4 gates contiguous
                for (int r = 0; r < 4; ++r) {
                    int m = bm * 128 + qm * 64 + i * 16 + quad * 4 + r;
                    if (m < 16016) {
                        int b = m / 1001;
                        int t = m - b * 1001;
                        size_t off = ((size_t)(t * 2 + dirg) * 16 + b) * 512 + s;
                        pre[off] = acc[i][j][r] + bias;
                    }
                }
            }
    }
}

// ---------------- feature build: gather harmonic energies from bf16 DFT output ----------------
__global__ __launch_bounds__(320) void build_feat(const float* __restrict__ f0,
    const __bf16* __restrict__ Cdft, __bf16* __restrict__ feat)
{
    int frame = blockIdx.x;
    int d = threadIdx.x;   // 0..319
    float val = 0.f;
    if (frame < 16016) {
        int b = frame / 1001;
        int t = frame - b * 1001;
        float f0v = f0[b * 1001 + t];
        float f0nz = (f0v > 0.f) ? f0v : 80.f;   // SR/NUM_BANDS*0.5
        if (d < 300) {
            float mult = (d == 0) ? 0.5f : (float)(d + 1) * 0.5f;
            float harm = f0nz * mult;
            int kidx = (int)rintf(harm * (1.0f / 11.71875f));  // FREQ_INTERVAL = 24000/2048
            kidx = min(max(kidx, 0), 1024);
            float e = 0.f;
            if (kidx < 1024) {   // bin 1024 forced to zero by reference
                unsigned int pk = *reinterpret_cast<const unsigned int*>(&Cdft[(size_t)frame * 2176 + 2 * kidx]);
                union { unsigned int u; __bf16 h[2]; } c; c.u = pk;
                float c0 = (float)c.h[0], c1 = (float)c.h[1];
                e = c0 * c0 + c1 * c1;
            }
            val = (logf(e + 1e-8f) + 18.f) * (1.f / 23.f);
        } else if (d == 300) {
            val = logf(f0nz);
        }
    }
    feat[(size_t)frame * 320 + d] = (__bf16)val;
}

// ---------------- stacked input-projection weights, transposed + K-padded, bf16 ----------------
__global__ __launch_bounds__(256) void build_wt(const float* __restrict__ w_ih_f,
    const float* __restrict__ w_ih_b, __bf16* __restrict__ WT)
{
    int id = blockIdx.x * 256 + threadIdx.x;
    if (id >= 1024 * 320) return;
    int n = id / 320;
    int k = id - n * 320;
    float v = 0.f;
    if (k < 301) v = (n < 512) ? w_ih_f[n * 301 + k] : w_ih_b[(n - 512) * 301 + k];
    WT[id] = (__bf16)v;
}

// ---------------- batch-parallel BiLSTM: 32 blocks = (batch 16) x (dir 2), one CU each.
// GEMV z = W_hh(512x128) . h(128) as MFMA with W preloaded in A-register-fragments
// (row-permuted s=4*j+gate so each acc f32x4 = all 4 gates of one cell). h broadcast via
// 256B LDS. 128 cells updated by threads 0..127. 2 lgkm-only barriers/step. ----------------
__global__ __launch_bounds__(512) void lstm_kernel(
    const float* __restrict__ w_hh_f, const float* __restrict__ w_hh_b,
    const float* __restrict__ pre, float* __restrict__ h_out)
{
    const int bid = blockIdx.x;          // 0..31
    const int b   = bid & 15;
    const int dir = bid >> 4;
    const float* w_hh = dir ? w_hh_b : w_hh_f;
    const int tid = threadIdx.x;
    const int wave = tid >> 6, lane = tid & 63, l15 = lane & 15, quad = lane >> 4;

    __shared__ __bf16 h_lds[128];        // h(t-1), bf16
    __shared__ float  z_lds[512];        // z in permuted order s = 4*j + g

    // A-fragments: perm row s = wave*64 + mt*16 + l15; holds W_hh[(s&3)*128 + (s>>2)][k]
    bf16x8 afrag[4][4];
    #pragma unroll
    for (int mt = 0; mt < 4; ++mt) {
        int s = wave * 64 + mt * 16 + l15;
        const float* wr = w_hh + (size_t)((s & 3) * 128 + (s >> 2)) * 128;
        #pragma unroll
        for (int kt = 0; kt < 4; ++kt) {
            bf16x8 v;
            #pragma unroll
            for (int e = 0; e < 8; ++e) v[e] = (__bf16)wr[kt * 32 + quad * 8 + e];
            afrag[mt][kt] = v;
        }
    }

    if (tid < 128) h_lds[tid] = (__bf16)0.f;

    const int t0 = dir ? 1000 : 0;
    const ptrdiff_t pre_stride  = (ptrdiff_t)(dir ? -1 : 1) * 2 * 16 * 512;
    const ptrdiff_t hout_stride = (ptrdiff_t)(dir ? -1 : 1) * 16 * 128;
    const float* pre_ptr  = pre + ((size_t)(t0 * 2 + dir) * 16 + b) * 512 + (size_t)tid * 4;
    float*       hout_ptr = h_out + (((size_t)dir * 1001 + t0) * 16 + b) * 128;

    float cstate = 0.f;
    f32x4 pc = {0.f, 0.f, 0.f, 0.f};
    if (tid < 128) pc = *reinterpret_cast<const f32x4*>(pre_ptr);
    __syncthreads();

    const float L2E = 1.4426950408889634f;
    for (int step = 0; step <= 1000; ++step) {
        // prefetch next step's pre (vmcnt stays in flight across lgkm-only barriers)
        f32x4 pn = pc;
        if (tid < 128 && step < 1000)
            pn = *reinterpret_cast<const f32x4*>(pre_ptr + pre_stride);
        pre_ptr += pre_stride;

        // B-fragments: h broadcast (n-replicated), 4x ds_read_b128
        bf16x8 bfr[4];
        #pragma unroll
        for (int kt = 0; kt < 4; ++kt)
            bfr[kt] = *reinterpret_cast<const bf16x8*>(&h_lds[kt * 32 + quad * 8]);

        f32x4 acc[4] = {};
        #pragma unroll
        for (int mt = 0; mt < 4; ++mt)
            #pragma unroll
            for (int kt = 0; kt < 4; ++kt)
                acc[mt] = __builtin_amdgcn_mfma_f32_16x16x32_bf16(afrag[mt][kt], bfr[kt], acc[mt], 0, 0, 0);

        // only column 0 (l15==0) is valid; rows quad*4+r = perm slots
        if (l15 == 0) {
            #pragma unroll
            for (int mt = 0; mt < 4; ++mt)
                *reinterpret_cast<f32x4*>(&z_lds[wave * 64 + mt * 16 + quad * 4]) = acc[mt];
        }
        sync_lds();   // z visible; also guarantees all bfr reads of h_lds are done

        if (tid < 128) {
            f32x4 z4 = *reinterpret_cast<const f32x4*>(&z_lds[tid * 4]);
            float zi = z4[0] + pc[0], zf = z4[1] + pc[1];
            float zg = z4[2] + pc[2], zo = z4[3] + pc[3];
            // fused gates: 5 exp2 + 2 rcp
            float A = __builtin_amdgcn_exp2f(-L2E * zi);
            float B = __builtin_amdgcn_exp2f(-L2E * zf);
            float C = __builtin_amdgcn_exp2f(-2.f * L2E * zg);
            float D = __builtin_amdgcn_exp2f(-L2E * zo);
            float P = (1.f + A) * (1.f + C);
            float Q = 1.f + B;
            float cn = (cstate * P + (1.f - C) * Q) * __builtin_amdgcn_rcpf(P * Q);
            cstate = cn;
            float E = __builtin_amdgcn_exp2f(-2.f * L2E * cn);
            float h = (1.f - E) * __builtin_amdgcn_rcpf((1.f + D) * (1.f + E));
            hout_ptr[tid] = h;                 // fire-and-forget
            h_lds[tid] = (__bf16)h;
        }
        hout_ptr += hout_stride;
        pc = pn;
        sync_lds();   // h(t) visible
    }
}

// ---------------- LayerNorm(concat(hf,hb)) + out projection; one wave per (b,t) row ----------------
__global__ __launch_bounds__(256) void out_kernel(
    const float* __restrict__ h_out, const float* __restrict__ ln_g, const float* __restrict__ ln_b,
    const float* __restrict__ out_w, const float* __restrict__ out_b, float* __restrict__ out)
{
    __shared__ __bf16 w_lds[256 * 66];   // [k][o], padded: conflict-free both directions
    __shared__ float hn_lds[4 * 256];
    const int tid = threadIdx.x;
    const int wave = tid >> 6, lane = tid & 63;
    for (int idx = tid; idx < 16384; idx += 256) {
        int o = idx >> 8, k = idx & 255;
        w_lds[k * 66 + o] = (__bf16)out_w[o * 256 + k];
    }
    int r = blockIdx.x * 4 + wave;       // < 16016
    int b = r / 1001, t = r - b * 1001;
    size_t basef = (((size_t)0 * 1001 + t) * 16 + b) * 128;
    size_t baseb = (((size_t)1 * 1001 + t) * 16 + b) * 128;
    float h0 = h_out[basef + lane];
    float h1 = h_out[basef + 64 + lane];
    float h2 = h_out[baseb + lane];
    float h3 = h_out[baseb + 64 + lane];
    float s1 = h0 + h1 + h2 + h3;
    float s2 = h0 * h0 + h1 * h1 + h2 * h2 + h3 * h3;
    #pragma unroll
    for (int m = 32; m >= 1; m >>= 1) {
        s1 += __shfl_xor(s1, m, 64);
        s2 += __shfl_xor(s2, m, 64);
    }
    float mu = s1 * (1.f / 256.f);
    float var = s2 * (1.f / 256.f) - mu * mu;   // biased var, matches jnp var
    float rstd = rsqrtf(var + 1e-5f);
    int k0 = lane, k1 = 64 + lane, k2 = 128 + lane, k3 = 192 + lane;
    hn_lds[wave * 256 + k0] = (h0 - mu) * rstd * ln_g[k0] + ln_b[k0];
    hn_lds[wave * 256 + k1] = (h1 - mu) * rstd * ln_g[k1] + ln_b[k1];
    hn_lds[wave * 256 + k2] = (h2 - mu) * rstd * ln_g[k2] + ln_b[k2];
    hn_lds[wave * 256 + k3] = (h3 - mu) * rstd * ln_g[k3] + ln_b[k3];
    __syncthreads();
    const float* hn = &hn_lds[wave * 256];
    float acc = 0.f;
    #pragma unroll 4
    for (int k = 0; k < 256; ++k)
        acc += hn[k] * (float)w_lds[k * 66 + lane];   // hn[k]: LDS broadcast
    out[(size_t)r * 64 + lane] = acc + out_b[lane];
}

extern "C" void kernel_launch(void* const* d_in, const int* in_sizes, int n_in,
                              void* d_out, int out_size, void* d_ws, size_t ws_size,
                              hipStream_t stream) {
    const float* x      = (const float*)d_in[0];
    const float* f0     = (const float*)d_in[1];
    const float* w_ih_f = (const float*)d_in[2];
    const float* w_hh_f = (const float*)d_in[3];
    const float* b_f    = (const float*)d_in[4];
    const float* w_ih_b = (const float*)d_in[5];
    const float* w_hh_b = (const float*)d_in[6];
    const float* b_b    = (const float*)d_in[7];
    const float* ln_g   = (const float*)d_in[8];
    const float* ln_b   = (const float*)d_in[9];
    const float* out_w  = (const float*)d_in[10];
    const float* out_b  = (const float*)d_in[11];
    float* out = (float*)d_out;

    char* ws = (char*)d_ws;
    size_t off = 0;
    auto alloc = [&](size_t bytes) { size_t o = off; off = (off + bytes + 255) & ~(size_t)255; return o; };
    __bf16* A     = (__bf16*)(ws + alloc((size_t)16128 * 960 * 2));
    __bf16* BT    = (__bf16*)(ws + alloc((size_t)2176 * 960 * 2));
    __bf16* Cdft  = (__bf16*)(ws + alloc((size_t)16128 * 2176 * 2));
    __bf16* feat  = (__bf16*)(ws + alloc((size_t)16128 * 320 * 2));
    __bf16* WT    = (__bf16*)(ws + alloc((size_t)1024 * 320 * 2));
    float*  pre   = (float*)(ws + alloc((size_t)1001 * 2 * 16 * 512 * 4));
    float*  h_out = (float*)(ws + alloc((size_t)2 * 1001 * 16 * 128 * 4));
    (void)ws_size; (void)in_sizes; (void)n_in; (void)out_size;

    build_bdft  <<<(2176 * 960 + 255) / 256, 256, 0, stream>>>(BT);
    build_frames<<<(16128 * 480 + 255) / 256, 256, 0, stream>>>(x, A);
    gemm_kernel <<<dim3(17, 126), 256, 0, stream>>>(A, BT, 960, 15, 0, Cdft, nullptr, nullptr, nullptr);
    build_feat  <<<16128, 320, 0, stream>>>(f0, Cdft, feat);
    build_wt    <<<(1024 * 320 + 255) / 256, 256, 0, stream>>>(w_ih_f, w_ih_b, WT);
    gemm_kernel <<<dim3(8, 126), 256, 0, stream>>>(feat, WT, 320, 5, 1, nullptr, pre, b_f, b_b);
    lstm_kernel <<<32, 512, 0, stream>>>(w_hh_f, w_hh_b, pre, h_out);
    out_kernel  <<<4004, 256, 0, stream>>>(h_out, ln_g, ln_b, out_w, out_b, out);
}